// Round 1
// baseline (81.995 us; speedup 1.0000x reference)
//
#include <hip/hip_runtime.h>
#include <math.h>

// Problem constants (from reference): B=32, E=1024, H=1024, N=128, L=64, K=8
#define NB 32
#define NE 1024
#define NH 1024
#define NN 128
#define NL 64
#define NK 8

// ---------------------------------------------------------------------------
// K1: scores[b,n] = dot(cache_keys[b,n,:], inputs[b,:])   (wave per (b,n))
// ---------------------------------------------------------------------------
__global__ void scores_kernel(const float* __restrict__ cache_keys,
                              const float* __restrict__ inputs,
                              float* __restrict__ scores) {
    int wid  = blockIdx.x * 4 + (threadIdx.x >> 6);   // 0..4095
    int lane = threadIdx.x & 63;
    int b = wid >> 7, n = wid & 127;
    const float4* ck = (const float4*)(cache_keys + ((size_t)b * NN + n) * NE);
    const float4* in = (const float4*)(inputs + (size_t)b * NE);
    float acc = 0.f;
#pragma unroll
    for (int c = 0; c < 4; ++c) {
        float4 a = ck[c * 64 + lane];
        float4 x = in[c * 64 + lane];
        acc += a.x * x.x + a.y * x.y + a.z * x.z + a.w * x.w;
    }
#pragma unroll
    for (int s = 32; s; s >>= 1) acc += __shfl_down(acc, s, 64);
    if (lane == 0) scores[b * NN + n] = acc;
}

// ---------------------------------------------------------------------------
// K2: per-batch top-8 + softmax -> weights, idx  (one wave per batch)
// Note: order of the K selected entries is irrelevant downstream (sum over k).
// ---------------------------------------------------------------------------
__global__ void topk_kernel(const float* __restrict__ scores,
                            int* __restrict__ top_idx,
                            float* __restrict__ weights) {
    int b = blockIdx.x;
    int lane = threadIdx.x;            // blockDim = 64
    float s0 = scores[b * NN + lane];
    float s1 = scores[b * NN + 64 + lane];
    __shared__ float tv[NK];
    for (int i = 0; i < NK; ++i) {
        float v = s0; int idx = lane;
        if (s1 > v) { v = s1; idx = lane + 64; }
#pragma unroll
        for (int s = 1; s < 64; s <<= 1) {
            float ov = __shfl_xor(v, s, 64);
            int   oi = __shfl_xor(idx, s, 64);
            if (ov > v || (ov == v && oi < idx)) { v = ov; idx = oi; }
        }
        if (lane == 0) { tv[i] = v; top_idx[b * NK + i] = idx; }
        if (idx == lane)      s0 = -INFINITY;
        if (idx == lane + 64) s1 = -INFINITY;
    }
    __syncthreads();
    if (lane < NK) {
        float e = expf(tv[lane] - tv[0]);   // tv[0] is the max
        float sum = e;
        sum += __shfl_xor(sum, 1, 64);
        sum += __shfl_xor(sum, 2, 64);
        sum += __shfl_xor(sum, 4, 64);
        weights[b * NK + lane] = e / sum;
    }
}

// ---------------------------------------------------------------------------
// K3/K8: C[b,o] = dot(A[b,:], W[o,:]) + bias[o]; wave per (o, 4-batch group)
// ---------------------------------------------------------------------------
template <int D>
__global__ void rowdot_kernel(const float* __restrict__ A,    // [NB][D]
                              const float* __restrict__ W,    // [NH][D]
                              const float* __restrict__ bias, // [NH]
                              float* __restrict__ C) {        // [NB][NH]
    int wid  = blockIdx.x * 4 + (threadIdx.x >> 6);   // 0..8191
    int lane = threadIdx.x & 63;
    int o  = wid >> 3;
    int bg = (wid & 7) * 4;
    const float4* Wr = (const float4*)(W + (size_t)o * D);
    const float4* A0 = (const float4*)(A + (size_t)(bg + 0) * D);
    const float4* A1 = (const float4*)(A + (size_t)(bg + 1) * D);
    const float4* A2 = (const float4*)(A + (size_t)(bg + 2) * D);
    const float4* A3 = (const float4*)(A + (size_t)(bg + 3) * D);
    float acc0 = 0.f, acc1 = 0.f, acc2 = 0.f, acc3 = 0.f;
#pragma unroll
    for (int c = 0; c < D / 256; ++c) {
        float4 w4 = Wr[c * 64 + lane];
        float4 a0 = A0[c * 64 + lane];
        float4 a1 = A1[c * 64 + lane];
        float4 a2 = A2[c * 64 + lane];
        float4 a3 = A3[c * 64 + lane];
        acc0 += w4.x * a0.x + w4.y * a0.y + w4.z * a0.z + w4.w * a0.w;
        acc1 += w4.x * a1.x + w4.y * a1.y + w4.z * a1.z + w4.w * a1.w;
        acc2 += w4.x * a2.x + w4.y * a2.y + w4.z * a2.z + w4.w * a2.w;
        acc3 += w4.x * a3.x + w4.y * a3.y + w4.z * a3.z + w4.w * a3.w;
    }
#pragma unroll
    for (int s = 32; s; s >>= 1) {
        acc0 += __shfl_down(acc0, s, 64);
        acc1 += __shfl_down(acc1, s, 64);
        acc2 += __shfl_down(acc2, s, 64);
        acc3 += __shfl_down(acc3, s, 64);
    }
    if (lane == 0) {
        float bb = bias[o];
        C[(size_t)(bg + 0) * NH + o] = acc0 + bb;
        C[(size_t)(bg + 1) * NH + o] = acc1 + bb;
        C[(size_t)(bg + 2) * NH + o] = acc2 + bb;
        C[(size_t)(bg + 3) * NH + o] = acc3 + bb;
    }
}

// ---------------------------------------------------------------------------
// K4: pqk[gs][b][h] = sum_{g in gs-chunk} query[b,g] * Wk[g,h]
// (bk dropped: q·bk is constant over l and cancels in the l-softmax)
// ---------------------------------------------------------------------------
__global__ void qk_partial_kernel(const float* __restrict__ query, // [NB][NH]
                                  const float* __restrict__ Wk,    // [NH][NH] (g,h)
                                  float* __restrict__ pqk) {       // [4][NB][NH]
    int b  = blockIdx.x >> 2;
    int gs = blockIdx.x & 3;
    int t  = threadIdx.x;             // 256 threads, float4 over h
    const float* q = query + (size_t)b * NH + gs * 256;
    const float4* Wr = (const float4*)Wk;
    float4 acc = make_float4(0.f, 0.f, 0.f, 0.f);
    for (int gg = 0; gg < 256; ++gg) {
        int g = gs * 256 + gg;
        float qv = q[gg];                         // uniform -> scalar load
        float4 w = Wr[(size_t)g * 256 + t];       // coalesced row access
        acc.x += qv * w.x; acc.y += qv * w.y;
        acc.z += qv * w.z; acc.w += qv * w.w;
    }
    ((float4*)pqk)[((size_t)gs * NB + b) * 256 + t] = acc;
}

// ---------------------------------------------------------------------------
// K5: per (b,k): logits[l] = (zones[l,:]·qk[b,:]) / sqrt(H); softmax over l;
//     coef[b,k,l] = weights[b,k] * attn[l]
// ---------------------------------------------------------------------------
__global__ void attn_kernel(const float* __restrict__ pqk,          // [4][NB][NH]
                            const float* __restrict__ cache_values, // [NB][NN][NL][NH]
                            const int* __restrict__ top_idx,        // [NB][NK]
                            const float* __restrict__ weights,      // [NB][NK]
                            float* __restrict__ coef) {             // [NB][NK][NL]
    int b = blockIdx.x >> 3;
    int k = blockIdx.x & 7;
    __shared__ float qk_lds[NH];
    __shared__ float logits[NL];
    int t = threadIdx.x;
    // reduce the 4 g-partials into LDS qk
    float4 s = make_float4(0.f, 0.f, 0.f, 0.f);
#pragma unroll
    for (int gs = 0; gs < 4; ++gs) {
        float4 p = ((const float4*)pqk)[((size_t)gs * NB + b) * 256 + t];
        s.x += p.x; s.y += p.y; s.z += p.z; s.w += p.w;
    }
    ((float4*)qk_lds)[t] = s;
    __syncthreads();

    int wv = t >> 6, lane = t & 63;
    int zi = top_idx[b * NK + k];
    const float* zbase = cache_values + (((size_t)b * NN + zi) * NL) * NH;
    for (int l = wv; l < NL; l += 4) {
        const float4* zr = (const float4*)(zbase + (size_t)l * NH);
        float acc = 0.f;
#pragma unroll
        for (int c = 0; c < 4; ++c) {
            float4 z  = zr[c * 64 + lane];
            float4 qv = ((const float4*)qk_lds)[c * 64 + lane];
            acc += z.x * qv.x + z.y * qv.y + z.z * qv.z + z.w * qv.w;
        }
#pragma unroll
        for (int sft = 32; sft; sft >>= 1) acc += __shfl_down(acc, sft, 64);
        if (lane == 0) logits[l] = acc * 0.03125f;   // 1/sqrt(1024)
    }
    __syncthreads();
    if (t < NL) {   // wave 0, all 64 lanes
        float v = logits[t];
        float m = v;
#pragma unroll
        for (int sft = 1; sft < 64; sft <<= 1) m = fmaxf(m, __shfl_xor(m, sft, 64));
        float e = expf(v - m);
        float sum = e;
#pragma unroll
        for (int sft = 1; sft < 64; sft <<= 1) sum += __shfl_xor(sum, sft, 64);
        coef[(b * NK + k) * NL + t] = weights[b * NK + k] * e / sum;
    }
}

// ---------------------------------------------------------------------------
// K6: patt[ks][b][h] = sum over 128 of the 512 (k,l) rows of coef*zones
// ---------------------------------------------------------------------------
__global__ void zonesum_kernel(const float* __restrict__ cache_values,
                               const int* __restrict__ top_idx,
                               const float* __restrict__ coef,
                               float* __restrict__ patt) {  // [4][NB][NH]
    int b  = blockIdx.x >> 2;
    int ks = blockIdx.x & 3;
    int t  = threadIdx.x;             // float4 over h
    float4 acc = make_float4(0.f, 0.f, 0.f, 0.f);
    for (int r = ks * 128; r < ks * 128 + 128; ++r) {
        int k = r >> 6, l = r & 63;
        int zi = top_idx[b * NK + k];
        float c = coef[(b * NK + k) * NL + l];
        const float4* zr = (const float4*)(cache_values +
                            (((size_t)b * NN + zi) * NL + l) * NH);
        float4 z = zr[t];
        acc.x += c * z.x; acc.y += c * z.y; acc.z += c * z.z; acc.w += c * z.w;
    }
    ((float4*)patt)[((size_t)ks * NB + b) * 256 + t] = acc;
}

// ---------------------------------------------------------------------------
// K7: F[b][0:1024] = sum_ks patt, F[b][1024:2048] = inputs[b]
// ---------------------------------------------------------------------------
__global__ void buildF_kernel(const float* __restrict__ patt,   // [4][NB][NH]
                              const float* __restrict__ inputs, // [NB][NE]
                              float* __restrict__ F) {          // [NB][2*NH]
    int gid = blockIdx.x * 256 + threadIdx.x;   // 0..16383 float4s
    int b = gid >> 9, j4 = gid & 511;
    float4 v;
    if (j4 < 256) {
        v = make_float4(0.f, 0.f, 0.f, 0.f);
#pragma unroll
        for (int ks = 0; ks < 4; ++ks) {
            float4 p = ((const float4*)patt)[((size_t)ks * NB + b) * 256 + j4];
            v.x += p.x; v.y += p.y; v.z += p.z; v.w += p.w;
        }
    } else {
        v = ((const float4*)(inputs + (size_t)b * NE))[j4 - 256];
    }
    ((float4*)F)[(size_t)b * 512 + j4] = v;
}

// ---------------------------------------------------------------------------
extern "C" void kernel_launch(void* const* d_in, const int* in_sizes, int n_in,
                              void* d_out, int out_size, void* d_ws, size_t ws_size,
                              hipStream_t stream) {
    const float* inputs       = (const float*)d_in[0];
    const float* Wq           = (const float*)d_in[1];
    const float* bq           = (const float*)d_in[2];
    const float* Wk           = (const float*)d_in[3];
    // d_in[4] = bk: q·bk is constant across l -> cancels in the l-softmax.
    const float* Wc           = (const float*)d_in[5];
    const float* bc           = (const float*)d_in[6];
    const float* cache_keys   = (const float*)d_in[7];
    const float* cache_values = (const float*)d_in[8];
    float* out = (float*)d_out;

    float* ws      = (float*)d_ws;
    float* scores  = ws;                 // 4096
    float* query   = scores + 4096;      // 32768
    float* pqk     = query + 32768;      // 131072
    float* coef    = pqk + 131072;       // 16384
    float* patt    = coef + 16384;       // 131072
    float* F       = patt + 131072;      // 65536
    float* weights = F + 65536;          // 256
    int*   tidx    = (int*)(weights + 256); // 256 ints
    (void)ws_size; (void)n_in; (void)in_sizes; (void)out_size;

    scores_kernel<<<1024, 256, 0, stream>>>(cache_keys, inputs, scores);
    topk_kernel<<<NB, 64, 0, stream>>>(scores, tidx, weights);
    rowdot_kernel<1024><<<2048, 256, 0, stream>>>(inputs, Wq, bq, query);
    qk_partial_kernel<<<128, 256, 0, stream>>>(query, Wk, pqk);
    attn_kernel<<<NB * NK, 256, 0, stream>>>(pqk, cache_values, tidx, weights, coef);
    zonesum_kernel<<<128, 256, 0, stream>>>(cache_values, tidx, coef, patt);
    buildF_kernel<<<64, 256, 0, stream>>>(patt, inputs, F);
    rowdot_kernel<2048><<<2048, 256, 0, stream>>>(F, Wc, bc, out);
}